// Round 1
// baseline (426.816 us; speedup 1.0000x reference)
//
#include <hip/hip_runtime.h>
#include <math.h>

// Problem constants (from reference setup_inputs)
#define BATCH 8
#define CIN 512
#define H 128
#define W 128
#define COUT 3
#define CHUNKS 16
#define CH (CIN / CHUNKS)      // 32 channels per chunk-block
#define TILE_H 32
#define TILES_Y (H / TILE_H)   // 4
#define LROWS (TILE_H + 2)     // 34 (with top/bottom halo)
#define LSTRIDE 132            // floats per LDS row: [0..2] slack, [3] = col -1 halo,
                               // [4..131] = cols 0..127; col 128 halo = next row's [0]
#define LDS_TILE (LROWS * LSTRIDE + 4)

__global__ __launch_bounds__(256) void torgb_conv(
    const float* __restrict__ in, const float* __restrict__ skip,
    const float* __restrict__ weight, const float* __restrict__ bias,
    float* __restrict__ out)
{
    __shared__ __align__(16) float lds[2][LDS_TILE];
    __shared__ float wlds[COUT * CH * 9];

    const int bx    = blockIdx.x;
    const int tile  = bx & (TILES_Y - 1);
    const int b     = (bx >> 2) & (BATCH - 1);
    const int chunk = bx >> 5;
    const int ci0   = chunk * CH;
    const int y0    = tile * TILE_H;

    const int tid = threadIdx.x;
    const int tx  = tid & (W - 1);   // column 0..127
    const int s   = tid >> 7;        // row strip 0/1
    const int py0 = s * 16;          // local row base

    // zero the halo columns once (never overwritten by staging)
    for (int r = tid; r < LROWS; r += 256) {
        lds[0][r * LSTRIDE + 3] = 0.f;
        lds[0][r * LSTRIDE + LSTRIDE] = 0.f;
        lds[1][r * LSTRIDE + 3] = 0.f;
        lds[1][r * LSTRIDE + LSTRIDE] = 0.f;
    }
    // this chunk's weights -> LDS (layout [co][ci][9], contiguous per co)
    for (int i = tid; i < COUT * CH * 9; i += 256) {
        int co  = i / (CH * 9);
        int rem = i - co * (CH * 9);
        wlds[i] = weight[co * (CIN * 9) + ci0 * 9 + rem];
    }

    const float* inb = in + (size_t)b * CIN * H * W;

    // prologue: stage channel 0 into buf 0
    {
        const float4* src = (const float4*)(inb + (size_t)ci0 * H * W);
        for (int i = tid; i < LROWS * (W / 4); i += 256) {
            int r = i >> 5, c4 = i & 31;
            int g = y0 - 1 + r;
            float4 v = make_float4(0.f, 0.f, 0.f, 0.f);
            if (g >= 0 && g < H) v = src[g * (W / 4) + c4];
            *(float4*)&lds[0][r * LSTRIDE + 4 + c4 * 4] = v;
        }
    }

    float acc[16][3];
#pragma unroll
    for (int p = 0; p < 16; p++)
#pragma unroll
        for (int c = 0; c < 3; c++) acc[p][c] = 0.f;

    for (int ci = 0; ci < CH; ci++) {
        __syncthreads();

        // --- issue global loads for ci+1 into registers (overlap with compute) ---
        const int nxt = ci + 1;
        const bool have = (nxt < CH);
        float4 pre[5];
        int pr[5], pc[5];
        if (have) {
            const float4* src = (const float4*)(inb + (size_t)(ci0 + nxt) * H * W);
#pragma unroll
            for (int k = 0; k < 4; k++) {
                int i = tid + k * 256;
                int r = i >> 5, c4 = i & 31;
                int g = y0 - 1 + r;
                pr[k] = r; pc[k] = c4;
                float4 v = make_float4(0.f, 0.f, 0.f, 0.f);
                if (g >= 0 && g < H) v = src[g * (W / 4) + c4];
                pre[k] = v;
            }
            if (tid < 64) {
                int i = 1024 + tid;
                int r = i >> 5, c4 = i & 31;
                int g = y0 - 1 + r;
                pr[4] = r; pc[4] = c4;
                float4 v = make_float4(0.f, 0.f, 0.f, 0.f);
                if (g >= 0 && g < H) v = src[g * (W / 4) + c4];
                pre[4] = v;
            }
        }

        // --- compute channel ci from LDS ---
        const float* Bp = &lds[ci & 1][py0 * LSTRIDE + 3 + tx];
        float wv[3][9];
#pragma unroll
        for (int co = 0; co < 3; co++)
#pragma unroll
            for (int k = 0; k < 9; k++)
                wv[co][k] = wlds[(co * CH + ci) * 9 + k];

        float r0[3], r1[3], r2[3];
#pragma unroll
        for (int j = 0; j < 3; j++) { r0[j] = Bp[j]; r1[j] = Bp[LSTRIDE + j]; }
#pragma unroll
        for (int p = 0; p < 16; p++) {
#pragma unroll
            for (int j = 0; j < 3; j++) r2[j] = Bp[(p + 2) * LSTRIDE + j];
#pragma unroll
            for (int co = 0; co < 3; co++)
                acc[p][co] += r0[0] * wv[co][0] + r0[1] * wv[co][1] + r0[2] * wv[co][2]
                            + r1[0] * wv[co][3] + r1[1] * wv[co][4] + r1[2] * wv[co][5]
                            + r2[0] * wv[co][6] + r2[1] * wv[co][7] + r2[2] * wv[co][8];
#pragma unroll
            for (int j = 0; j < 3; j++) { r0[j] = r1[j]; r1[j] = r2[j]; }
        }

        // --- write the prefetched channel into the other LDS buffer ---
        if (have) {
            const int bufi = nxt & 1;
#pragma unroll
            for (int k = 0; k < 4; k++)
                *(float4*)&lds[bufi][pr[k] * LSTRIDE + 4 + pc[k] * 4] = pre[k];
            if (tid < 64)
                *(float4*)&lds[bufi][pr[4] * LSTRIDE + 4 + pc[4] * 4] = pre[4];
        }
    }

    // ---------------- epilogue ----------------
    const float scale = 1.0f / sqrtf((float)(CIN * 9));
    float* outb = out + (size_t)b * COUT * H * W;

    // horizontal skip-upsample taps (separable [0.25 0.75 0.75 0.25])
    int j0, j1; float wh0, wh1;
    if ((tx & 1) == 0) { j0 = tx >> 1;       wh0 = 0.75f; j1 = (tx >> 1) - 1; wh1 = 0.25f; }
    else               { j0 = (tx + 1) >> 1; wh0 = 0.25f; j1 = (tx - 1) >> 1; wh1 = 0.75f; }
    const bool j0ok = (j0 >= 0 && j0 < 64), j1ok = (j1 >= 0 && j1 < 64);

#pragma unroll
    for (int p = 0; p < 16; p++) {
        int y = y0 + py0 + p;
        int i0, i1; float wv0, wv1;
        if ((y & 1) == 0) { i0 = y >> 1;       wv0 = 0.75f; i1 = (y >> 1) - 1; wv1 = 0.25f; }
        else              { i0 = (y + 1) >> 1; wv0 = 0.25f; i1 = (y - 1) >> 1; wv1 = 0.75f; }
        const bool i0ok = (i0 >= 0 && i0 < 64), i1ok = (i1 >= 0 && i1 < 64);
#pragma unroll
        for (int co = 0; co < 3; co++) {
            float v = acc[p][co] * scale;
            if (chunk == 0) {
                const float* sk = skip + (size_t)(b * COUT + co) * 64 * 64;
                float s00 = (i0ok && j0ok) ? sk[i0 * 64 + j0] : 0.f;
                float s01 = (i0ok && j1ok) ? sk[i0 * 64 + j1] : 0.f;
                float s10 = (i1ok && j0ok) ? sk[i1 * 64 + j0] : 0.f;
                float s11 = (i1ok && j1ok) ? sk[i1 * 64 + j1] : 0.f;
                v += bias[co] + wv0 * (wh0 * s00 + wh1 * s01)
                              + wv1 * (wh0 * s10 + wh1 * s11);
            }
            atomicAdd(&outb[(size_t)co * H * W + y * W + tx], v);
        }
    }
}

extern "C" void kernel_launch(void* const* d_in, const int* in_sizes, int n_in,
                              void* d_out, int out_size, void* d_ws, size_t ws_size,
                              hipStream_t stream) {
    const float* in     = (const float*)d_in[0];
    const float* skip   = (const float*)d_in[1];
    const float* weight = (const float*)d_in[2];
    const float* bias   = (const float*)d_in[3];
    float* out = (float*)d_out;

    hipMemsetAsync(out, 0, (size_t)out_size * sizeof(float), stream);
    dim3 grid(CHUNKS * BATCH * TILES_Y);  // 512 blocks
    torgb_conv<<<grid, 256, 0, stream>>>(in, skip, weight, bias, out);
}